// Round 15
// baseline (215.172 us; speedup 1.0000x reference)
//
#include <hip/hip_runtime.h>
#include <cmath>

// ---------------------------------------------------------------------------
// g_s: 4x chained conv_transpose2d(k=5,s=2,p=2,op=1) + integer quant epilogue.
// Hermite: sum_j floor((round(w)+j)/split) == round(w) -> one conv per layer.
// Exact i8: weights round(w) in [-127,127]; activations (x-128) in i8; OOB
// halo = -128 so conv_i8 = conv_ref(x) - 128*tapsum[parity][co] (exact i32).
//
// v21 (from v20 @198.0; band 194-198 = plateau +-2-3us noise): new mechanism
// from re-deriving the single-b critical path: dma_x(next) drains at the SAME
// barrier-B vmcnt(0) as dma_b, so the xs double buffer hides NOTHING in
// single-b kernels — 5.8KB pure waste. v21: L2/L3 go single-x+single-b (both
// DMAs issued at chunk top, one shared L2 round trip; identical critical
// path), LDS 37.4->31.4KB -> 5 blocks/CU (launch_bounds(256,5)) = 25% more
// overlap partners for the exposed-DMA + epilogue phases. L1 keeps the true
// 1-barrier dbuf pipeline (prefetch IS hidden there); L4 unchanged.
// Prior locked-in findings: direct __shared__ only (no LDS pointer args);
// R=2 for L2/L3/L4; bank-conflict door closed; trunc-fold epilogue.
// ---------------------------------------------------------------------------

typedef int int4v  __attribute__((ext_vector_type(4)));
typedef int int16v __attribute__((ext_vector_type(16)));

#define GLOBAL_AS __attribute__((address_space(1)))
#define LDS_AS    __attribute__((address_space(3)))

// async global->LDS, 16B per lane; LDS dest linear in lane (base+lane*16).
__device__ __forceinline__ void dma16(const signed char* g, signed char* l) {
    __builtin_amdgcn_global_load_lds((const GLOBAL_AS int*)g, (LDS_AS int*)l,
                                     16, 0, 0);
}

// tap id -> (ky,kx). Taps 0-8: EE; 9-14: EO; 15-20: OE; 21-24: OO.
__device__ __forceinline__ void tap_to_k(int t, int& ky, int& kx) {
    if (t < 9)       { int dy = t/3,  dx = t%3;                   ky = 4-2*dy; kx = 4-2*dx; }
    else if (t < 15) { int u = t-9;   int dy = u/2, dx = 1+(u&1);  ky = 4-2*dy; kx = 5-2*dx; }
    else if (t < 21) { int u = t-15;  int dy = 1+u/3, dx = u%3;    ky = 5-2*dy; kx = 4-2*dx; }
    else             { int u = t-21;  int dy = 1+u/2, dx = 1+(u&1); ky = 5-2*dy; kx = 5-2*dx; }
}

// Fused prep (barrier-free; parts independent): bid<180: convert f32 NCHW ->
// i8 NHWC; 180..311: packA (tapsum -> per-qs plain stores, NO atomics);
// 312..365: pack_w4; 366..371: tap_w4 (+ bid==366 hi-half fills xpad).
__global__ __launch_bounds__(256)
void prep_all(const float* __restrict__ x, signed char* __restrict__ xh,
              const float* __restrict__ w1, const float* __restrict__ w2,
              const float* __restrict__ w3, const float* __restrict__ w4,
              signed char* __restrict__ p1, signed char* __restrict__ p2,
              signed char* __restrict__ p3, signed char* __restrict__ p4,
              int* __restrict__ tsp1, int* __restrict__ tsp2,
              int* __restrict__ tsp3, int* __restrict__ t4,
              int* __restrict__ xpadw) {
    __shared__ __align__(16) signed char smem[26112];
    const int bid = blockIdx.x;
    const int tid = threadIdx.x;

    if (bid < 180) {
        float (*t)[65] = (float(*)[65])smem;         // 16,640 B
        const int C = 320, HW = 48 * 48;
        const int p0 = (bid % 36) * 64;
        const int c0 = (bid / 36) * 64;
        const int pL = tid & 63;
        const int r0 = tid >> 6;
        #pragma unroll
        for (int k = 0; k < 16; ++k) {
            int ciL = r0 * 16 + k;
            t[ciL][pL] = x[(size_t)(c0 + ciL) * HW + p0 + pL];
        }
        __syncthreads();
        #pragma unroll
        for (int k = 0; k < 16; ++k) {
            int pL2 = r0 * 16 + k;
            xh[(size_t)(p0 + pL2) * C + c0 + pL] = (signed char)((int)t[pL][pL2] - 128);
        }
    } else if (bid < 312) {
        int u = bid - 180;
        int layer, s;
        if (u < 60)      { layer = 0; s = u; }
        else if (u < 96) { layer = 1; s = u - 60; }
        else             { layer = 2; s = u - 96; }
        const float* w = (layer == 0) ? w1 : (layer == 1) ? w2 : w3;
        signed char* out = (layer == 0) ? p1 : (layer == 1) ? p2 : p3;
        int* tsp = (layer == 0) ? tsp1 : (layer == 1) ? tsp2 : tsp3;
        const int Cout = 192;
        const int qs = s / 6, nb = s % 6;

        signed char* ls = smem;                       // 25,600
        int (*lsum)[32] = (int(*)[32])(smem + 25600); // 512
        if (tid < 128) ((int*)lsum)[tid] = 0;
        __syncthreads();

        #pragma unroll
        for (int k = 0; k < 4; ++k) {
            const int pidx = tid + k * 256;
            const int cil = pidx >> 5;
            const int colp = pidx & 31;
            const int ci = qs * 32 + cil;
            const int cop = nb * 32 + colp;
            const float* wr = w + (size_t)(ci * Cout + cop) * 25;
            const int halfp = cil >> 4, j = cil & 15;
            const int base = (halfp * 32 + colp) * 16 + j;
            int psum[4] = {0, 0, 0, 0};
            #pragma unroll
            for (int tt = 0; tt < 25; ++tt) {
                int ky, kx; tap_to_k(tt, ky, kx);
                float v = rintf(wr[ky * 5 + kx]);
                v = fminf(fmaxf(v, -128.0f), 127.0f);
                int iv = (int)v;
                ls[tt * 1024 + base] = (signed char)iv;
                psum[((ky & 1) << 1) | (kx & 1)] += iv;
            }
            #pragma unroll
            for (int p = 0; p < 4; ++p) atomicAdd(&lsum[p][colp], psum[p]);
        }
        __syncthreads();

        signed char* dst = out + (size_t)s * 25600;
        for (int i = tid; i < 1600; i += 256)
            *(int4v*)&dst[i * 16] = *(const int4v*)&ls[i * 16];
        if (tid < 128) {
            // per-qs partial: written exactly once (this block owns (qs,nb))
            const int p = tid >> 5, colp = tid & 31;
            tsp[(qs * 4 + p) * Cout + nb * 32 + colp] = lsum[p][colp];
        }
    } else if (bid < 366) {
        const int bx = bid - 312;
        #pragma unroll
        for (int k = 0; k < 4; ++k) {
            int idx = bx * 1024 + k * 256 + tid;
            int j    = idx & 15;
            int lane = (idx >> 4) & 63;
            int rem  = idx >> 10;
            int s9   = rem % 9;
            int qs   = rem / 9;
            int colp = lane & 31;
            int cop  = colp & 7;
            int p    = colp >> 3;
            int py = p >> 1, px = p & 1;
            int dy = s9 / 3, dx = s9 % 3;
            int ci = qs * 32 + ((lane >> 5) << 4) + j;
            bool part = (py == 0 || dy >= 1) && (px == 0 || dx >= 1);
            float v = 0.0f;
            if (cop < 3 && part) {
                int ky = py ? 5 - 2 * dy : 4 - 2 * dy;
                int kx = px ? 5 - 2 * dx : 4 - 2 * dx;
                v = rintf(w4[(size_t)(ci * 3 + cop) * 25 + ky * 5 + kx]);
                v = fminf(fmaxf(v, -128.0f), 127.0f);
            }
            p4[idx] = (signed char)(int)v;
        }
    } else {
        if (tid < 128) {
            const int Cin = 192, Cout = 3;
            const int u = (bid - 366) * 2 + (tid >> 6);
            const int lane = tid & 63;
            const int cop = u % Cout, p = u / Cout;
            const int py = p >> 1, px = p & 1;
            const int nky = (5 - py + 1) >> 1;
            const int nkx = (5 - px + 1) >> 1;
            const int ntap = nky * nkx;
            int sacc = 0;
            for (int idx = lane; idx < Cin * ntap; idx += 64) {
                const int ci = idx / ntap;
                const int uu = idx - ci * ntap;
                const int ky = py + 2 * (uu / nkx);
                const int kx = px + 2 * (uu % nkx);
                float v = rintf(w4[(size_t)(ci * Cout + cop) * 25 + ky * 5 + kx]);
                v = fminf(fmaxf(v, -128.0f), 127.0f);
                sacc += (int)v;
            }
            #pragma unroll
            for (int off = 32; off > 0; off >>= 1)
                sacc += __shfl_down(sacc, off, 64);
            if (lane == 0) t4[u] = sacc;
        } else if (bid == 366) {
            // xpad fill (consumed only by later dispatches)
            xpadw[tid - 128] = (int)0x80808080;
        }
    }
}

// Per-role tap tables for parity-split (role0: EE(acc0)+OO(acc1);
// role1: EO(acc0)+OE(acc1)). Verified against the full shift/tap/parity map.
__device__ __forceinline__ constexpr int role_nt(int role, int s9) {
    constexpr int NT0[9] = {1,1,1,1,2,2,1,2,2};
    constexpr int NT1[9] = {0,1,1,1,2,2,1,2,2};
    return role == 0 ? NT0[s9] : NT1[s9];
}
__device__ __forceinline__ constexpr int role_tap(int role, int s9, int u) {
    constexpr int T0[9][2] = {{0,0},{1,0},{2,0},{3,0},{4,21},{5,22},{6,0},{7,23},{8,24}};
    constexpr int T1[9][2] = {{0,0},{9,0},{10,0},{15,0},{11,16},{12,17},{18,0},{13,19},{14,20}};
    return role == 0 ? T0[s9][u] : T1[s9][u];
}
__device__ __forceinline__ constexpr int role_acc(int role, int s9, int u) {
    constexpr int A0[9][2] = {{0,0},{0,0},{0,0},{0,0},{0,1},{0,1},{0,0},{0,1},{0,1}};
    constexpr int A1[9][2] = {{0,0},{0,0},{0,0},{1,0},{0,1},{0,1},{1,0},{0,1},{0,1}};
    return role == 0 ? A0[s9][u] : A1[s9][u];
}

// xs layout: [pix][32B] linear (per-s9 offsets fold into ds_read immediates).
template<int ROLE, int R>
__device__ __forceinline__ void compute_role(const signed char* xsb, const signed char* bsb,
                                             int16v (&acc)[R][2], const int (&p0)[R],
                                             int half, int lane) {
    #pragma unroll
    for (int s9 = 0; s9 < 9; ++s9) {
        if (role_nt(ROLE, s9) == 0) continue;
        const int dy = s9 / 3, dx = s9 % 3;
        int4v a[R];
        #pragma unroll
        for (int r = 0; r < R; ++r)
            a[r] = *(const int4v*)&xsb[(p0[r] + dy * 18 + dx) * 32 + half * 16];
        #pragma unroll
        for (int u = 0; u < 2; ++u) {
            if (u < role_nt(ROLE, s9)) {
                int4v b = *(const int4v*)&bsb[role_tap(ROLE, s9, u) * 1024 + lane * 16];
                const int ai = role_acc(ROLE, s9, u);
                #pragma unroll
                for (int r = 0; r < R; ++r)
                    acc[r][ai] = __builtin_amdgcn_mfma_i32_32x32x32_i8(a[r], b, acc[r][ai], 0, 0, 0);
            }
        }
    }
}

// Layers 1-3 (direct __shared__ in template __global__): MW waves = MW/2
// pairs x R subtiles. BDBUF: x+b dbuf, 1 barrier/chunk (true prefetch
// pipeline). !BDBUF: x AND b single-buffered — dma_x(next) drained at the
// same barrier-B vmcnt(0) as dma_b anyway, so dbuf-x hid nothing; single-x
// saves 5.8KB -> LDS 31.4KB -> 5 blocks/CU. T8>0: XCD-grouped decode.
template<int MW, int R, bool BDBUF, int TAG>
__global__ __launch_bounds__(MW * 64, BDBUF ? 4 : 5)
void deconv_v21(const signed char* __restrict__ xin, const signed char* __restrict__ wpk,
                const float* __restrict__ bias, const float* __restrict__ muls,
                const int* __restrict__ tsp, int QS,
                const float* __restrict__ relus, const int* __restrict__ dvds,
                const int* __restrict__ bitsp, const signed char* __restrict__ xpad,
                int layer, int Cin, int Cout, int NT, int Hq, int Wq,
                int NB, int NQX, int T8,
                signed char* __restrict__ outp) {
    constexpr int PAIRS = MW / 2;
    constexpr int QROWS = PAIRS * R * 2;
    constexpr int NROW = QROWS + 2;
    constexpr int NPIX = NROW * 18;
    constexpr int THREADS = MW * 64;
    constexpr int XC = NPIX * 2;
    constexpr int XI = (XC + THREADS - 1) / THREADS;
    constexpr int BC = 1600;
    constexpr int BI = (BC + THREADS - 1) / THREADS;
    constexpr int NBS = BDBUF ? 2 : 1;
    constexpr int NXS = BDBUF ? 2 : 1;

    __shared__ __align__(16) signed char xs[NXS][NPIX * 32];
    __shared__ __align__(16) signed char bs[NBS][25600];

    const int tid  = threadIdx.x;
    const int lane = tid & 63;
    const int wid  = tid >> 6;
    const int pairId = wid >> 1;
    const int role   = wid & 1;

    int nb, qx, qy;
    {
        const int bi = blockIdx.x;
        if (T8 > 0) {
            const int xcd = bi & 7, j = bi >> 3;
            const int tl = j / NB, n = j - tl * NB;
            const int tile = xcd * T8 + tl;
            nb = n; qx = tile % NQX; qy = tile / NQX;
        } else {
            nb = bi % NB;
            const int s = bi / NB;
            qx = s % NQX; qy = s / NQX;
        }
    }
    const int qx0 = qx * 16;
    const int qy0 = qy * QROWS;
    const int n0  = nb * 32;

    int16v acc[R][2];
    #pragma unroll
    for (int r = 0; r < R; ++r)
        #pragma unroll
        for (int p = 0; p < 2; ++p)
            #pragma unroll
            for (int e = 0; e < 16; ++e) acc[r][p][e] = 0;

    const int half   = lane >> 5;
    const int rowbit = (lane >> 4) & 1;
    const int col    = lane & 15;
    int p0[R];
    #pragma unroll
    for (int r = 0; r < R; ++r)
        p0[r] = ((pairId * R + r) * 2 + rowbit) * 18 + col;

    // per-slot DMA source base (ck added later; OOB -> xpad, +ck stays in pad)
    const signed char* xsrc[XI];
    #pragma unroll
    for (int t = 0; t < XI; ++t) {
        int i = tid + t * THREADS;
        xsrc[t] = xpad;
        if (i < XC) {
            int pix = i >> 1, g = i & 1;
            int rr = pix / 18, cc = pix - rr * 18;
            int y = qy0 - 1 + rr, xx = qx0 - 1 + cc;
            bool ok = (unsigned)y < (unsigned)Hq && (unsigned)xx < (unsigned)Wq;
            xsrc[t] = ok ? (xin + ((size_t)y * Wq + xx) * Cin + g * 16)
                         : (xpad + g * 16);
        }
    }

    auto dma_x = [&](int ck, int b) {
        #pragma unroll
        for (int t = 0; t < XI; ++t) {
            int i = tid + t * THREADS;
            if (i < XC) dma16(xsrc[t] + ck, &xs[b][i * 16]);
        }
    };
    auto dma_b = [&](int cs, int b) {
        const signed char* ws = wpk + (size_t)(cs * NT + nb) * 25600;
        #pragma unroll
        for (int t = 0; t < BI; ++t) {
            int i = tid + t * THREADS;
            if (i < BC) dma16(ws + (size_t)i * 16, &bs[b][i * 16]);
        }
    };

    if (BDBUF) { dma_x(0, 0); dma_b(0, 0); }
    for (int ck = 0, s = 0; ck < Cin; ck += 32, ++s) {
        if (BDBUF) {
            const int cb = s & 1;
            __syncthreads();   // vmcnt(0) drain -> DMA(cur) landed; all waves
                               // done reading bufs before next overwrite
            if (ck + 32 < Cin) {
                dma_x((s + 1) * 32, cb ^ 1);
                dma_b(s + 1, cb ^ 1);
            }
            if (role == 0) compute_role<0, R>(xs[cb], bs[cb & (NBS - 1)], acc, p0, half, lane);
            else           compute_role<1, R>(xs[cb], bs[cb & (NBS - 1)], acc, p0, half, lane);
        } else {
            __syncthreads();   // A: all waves done reading xs/bs (prev chunk)
            dma_b(s, 0);       // single buffers; one shared L2 round trip
            dma_x(s * 32, 0);
            __syncthreads();   // B: per-wave vmcnt(0) -> x and b landed
            if (role == 0) compute_role<0, R>(xs[0], bs[0], acc, p0, half, lane);
            else           compute_role<1, R>(xs[0], bs[0], acc, p0, half, lane);
        }
    }

    // ----- quant epilogue (exact fp32 op sequence; proven absmax 0.0) --------
    const int dv = dvds[layer];
    float add1 = ldexpf(1.0f, dv - 10);
    float inv1 = ldexpf(1.0f, -(dv - 9));
    const float relu = relus[layer];
    const int sk = (layer == 1) ? 4 : 3;
    const float bitsv = ldexpf(1.0f, bitsp[0]) - 1.0f;
    float clp, scl;
    {
        #pragma clang fp contract(off)
        clp = rintf(bitsv / relu * 33554432.0f);
        scl = floorf((relu + ldexpf(1.0f, sk - 1)) * ldexpf(1.0f, -sk));
    }
    float add2 = ldexpf(1.0f, 24 - sk);
    float inv2 = ldexpf(1.0f, -(25 - sk));

    const int co = n0 + (lane & 31);
    float bq = rintf(bias[co]);
    float mm = muls[co];
    // wave's two parities: role0 -> {EE=0, OO=3}; role1 -> {EO=1, OE=2}
    int pmap[2];
    pmap[0] = role == 0 ? 0 : 1;
    pmap[1] = role == 0 ? 3 : 2;
    // tapsum = sum of QS per-qs partials (exact integer adds; no atomics)
    int fullp[2] = {0, 0};
    for (int q = 0; q < QS; ++q) {
        fullp[0] += tsp[(q * 4 + pmap[0]) * Cout + co];
        fullp[1] += tsp[(q * 4 + pmap[1]) * Cout + co];
    }

    const int Wout = Wq * 2;

    #pragma unroll
    for (int r = 0; r < R; ++r) {
        #pragma unroll
        for (int a = 0; a < 2; ++a) {
            const int p = pmap[a];
            const int py = p >> 1, px = p & 1;
            #pragma unroll
            for (int reg = 0; reg < 16; ++reg) {
                const int mrow = (reg & 3) + 8 * (reg >> 2) + 4 * (lane >> 5);
                const int qy2 = qy0 + (pairId * R + r) * 2 + (mrow >> 4);
                const int qx2 = qx0 + (mrow & 15);
                float v = (float)(acc[r][a][reg] + 128 * fullp[a]);
                int iv;
                {
                    #pragma clang fp contract(off)
                    v = (v + bq) * mm;
                    v = floorf((v + add1) * inv1);
                    v = fminf(fmaxf(v, 0.0f), clp);
                    iv = (int)((v * scl + add2) * inv2);   // trunc == floor (v>=0)
                }
                const int oy = 2 * qy2 + py, ox = 2 * qx2 + px;
                outp[((size_t)oy * Wout + ox) * Cout + co] = (signed char)(iv - 128);
            }
        }
    }
}

// Final layer: N = (parity,co) columns, 1 MFMA per shift, R=2, MW=4 (576
// blocks); x+b DMA double-buffered, 1 barrier/chunk; output staged in LDS
// (obuf aliases dead xs/bs after K-loop) then stored as 128B-contiguous rows.
__global__ __launch_bounds__(256, 4)
void deconv_final_v21(const signed char* __restrict__ xin, const signed char* __restrict__ wpk,
                      const float* __restrict__ bias, const float* __restrict__ muls,
                      const int* __restrict__ tsum, const int* __restrict__ dvds,
                      const signed char* __restrict__ xpad,
                      int Cin, int Hq, int Wq, float* __restrict__ outp) {
    constexpr int R = 2, MW = 4;
    constexpr int QROWS = MW * R * 2;      // 16
    constexpr int NROW = QROWS + 2;        // 18
    constexpr int NPIX = NROW * 18;        // 324
    constexpr int THREADS = 256;
    constexpr int XC = NPIX * 2;           // 648
    constexpr int XI = (XC + THREADS - 1) / THREADS;   // 3
    constexpr int BC = 576;
    constexpr int BI = (BC + THREADS - 1) / THREADS;   // 3
    constexpr int XBUF = NPIX * 32;        // 10368

    // xs/bs during K-loop; obuf (3x32x32 f32 = 12,288B) aliases them after.
    __shared__ __align__(16) signed char smem[2 * XBUF + 2 * 9216]; // 39,168
    signed char (*xs)[XBUF] = (signed char(*)[XBUF])smem;
    signed char (*bs)[9216] = (signed char(*)[9216])(smem + 2 * XBUF);
    float* obuf = (float*)smem;

    const int tid  = threadIdx.x;
    const int lane = tid & 63;
    const int wid  = tid >> 6;
    const int qx0  = blockIdx.y * 16;
    const int qy0  = blockIdx.z * QROWS;

    int16v acc[R];
    #pragma unroll
    for (int r = 0; r < R; ++r)
        #pragma unroll
        for (int e = 0; e < 16; ++e) acc[r][e] = 0;

    const int half   = lane >> 5;
    const int rowbit = (lane >> 4) & 1;
    const int col    = lane & 15;
    int p0[R];
    #pragma unroll
    for (int r = 0; r < R; ++r)
        p0[r] = ((wid * R + r) * 2 + rowbit) * 18 + col;

    const signed char* xsrc[XI];
    #pragma unroll
    for (int t = 0; t < XI; ++t) {
        int i = tid + t * THREADS;
        xsrc[t] = xpad;
        if (i < XC) {
            int pix = i >> 1, g = i & 1;
            int rr = pix / 18, cc = pix - rr * 18;
            int y = qy0 - 1 + rr, xx = qx0 - 1 + cc;
            bool ok = (unsigned)y < (unsigned)Hq && (unsigned)xx < (unsigned)Wq;
            xsrc[t] = ok ? (xin + ((size_t)y * Wq + xx) * Cin + g * 16)
                         : (xpad + g * 16);
        }
    }

    auto dma_x = [&](int ck, int b) {
        #pragma unroll
        for (int t = 0; t < XI; ++t) {
            int i = tid + t * THREADS;
            if (i < XC) dma16(xsrc[t] + ck, &xs[b][i * 16]);
        }
    };
    auto dma_b = [&](int cs, int b) {
        const signed char* ws = wpk + (size_t)cs * 9216;
        #pragma unroll
        for (int t = 0; t < BI; ++t) {
            int i = tid + t * THREADS;
            if (i < BC) dma16(ws + (size_t)i * 16, &bs[b][i * 16]);
        }
    };

    dma_x(0, 0);
    dma_b(0, 0);
    for (int ck = 0; ck < Cin; ck += 32) {
        const int cb = (ck >> 5) & 1;
        __syncthreads();
        if (ck + 32 < Cin) {
            dma_x(ck + 32, cb ^ 1);
            dma_b((ck >> 5) + 1, cb ^ 1);
        }
        #pragma unroll
        for (int s9 = 0; s9 < 9; ++s9) {
            const int dy = s9 / 3, dx = s9 % 3;
            int4v b = *(const int4v*)&bs[cb][s9 * 1024 + lane * 16];
            #pragma unroll
            for (int r = 0; r < R; ++r) {
                int4v a = *(const int4v*)&xs[cb][(p0[r] + dy * 18 + dx) * 32 + half * 16];
                acc[r] = __builtin_amdgcn_mfma_i32_32x32x32_i8(a, b, acc[r], 0, 0, 0);
            }
        }
    }

    const int dv = dvds[3];
    const float add1 = ldexpf(1.0f, dv - 9);
    const float inv1 = ldexpf(1.0f, -(dv - 8));

    const int coln = lane & 31;
    const int co = coln & 7;
    const int p  = coln >> 3;
    const int py = p >> 1, px = p & 1;
    const bool valid = (co < 3);
    float bq = 0.f, mm = 0.f;
    int fp = 0;
    if (valid) { bq = rintf(bias[co]); mm = muls[co]; fp = tsum[p * 3 + co]; }

    __syncthreads();   // all waves done reading xs/bs (obuf aliases them)

    // epilogue -> obuf[co][ly][lx] (local 32x32 px block per co plane)
    #pragma unroll
    for (int r = 0; r < R; ++r) {
        #pragma unroll
        for (int reg = 0; reg < 16; ++reg) {
            const int mrow = (reg & 3) + 8 * (reg >> 2) + 4 * (lane >> 5);
            const int lq_y = (wid * R + r) * 2 + (mrow >> 4);   // 0..15
            const int lq_x = mrow & 15;                          // 0..15
            float v = (float)(acc[r][reg] + 128 * fp);
            {
                #pragma clang fp contract(off)
                v = (v + bq) * mm;
                v = floorf((v + add1) * inv1);   // keep floorf: v may be negative
                v = v / 255.0f;
            }
            if (valid) {
                const int ly = 2 * lq_y + py, lx = 2 * lq_x + px;
                obuf[co * 1024 + ly * 32 + lx] = v;
            }
        }
    }
    __syncthreads();

    // coalesced store: 3072 floats = 96 rows of 32 floats (128B contiguous)
    const int Wout = Wq * 2, Hout = Hq * 2;
    const int oyb = qy0 * 2, oxb = qx0 * 2;
    #pragma unroll
    for (int k = 0; k < 12; ++k) {
        const int idx = tid + k * 256;
        const int c  = idx >> 10;
        const int rem = idx & 1023;
        const int ly = rem >> 5, lx = rem & 31;
        outp[((size_t)c * Hout + oyb + ly) * Wout + oxb + lx] = obuf[idx];
    }
}

extern "C" void kernel_launch(void* const* d_in, const int* in_sizes, int n_in,
                              void* d_out, int out_size, void* d_ws, size_t ws_size,
                              hipStream_t stream) {
    const float* x  = (const float*)d_in[0];
    const float* w1 = (const float*)d_in[1];
    const float* b1 = (const float*)d_in[2];
    const float* w2 = (const float*)d_in[3];
    const float* b2 = (const float*)d_in[4];
    const float* w3 = (const float*)d_in[5];
    const float* b3 = (const float*)d_in[6];
    const float* w4 = (const float*)d_in[7];
    const float* b4 = (const float*)d_in[8];
    const float* m0 = (const float*)d_in[9];
    const float* m1 = (const float*)d_in[10];
    const float* m2 = (const float*)d_in[11];
    const float* m3 = (const float*)d_in[12];
    const float* relus = (const float*)d_in[13];
    const int* dvds = (const int*)d_in[14];
    const int* bitsp = (const int*)d_in[15];

    signed char* wsb = (signed char*)d_ws;
    size_t o = 0;
    signed char* wpk1 = wsb + o; o += (size_t)10 * 6 * 25600;   // 1,536,000
    signed char* wpk2 = wsb + o; o += (size_t)6 * 6 * 25600;    //   921,600
    signed char* wpk3 = wsb + o; o += (size_t)6 * 6 * 25600;
    signed char* wpk4 = wsb + o; o += (size_t)6 * 9216;         //    55,296
    // per-qs tapsum partials (plain stores, no zeroing needed)
    int* tsp1 = (int*)(wsb + o); o += 10 * 4 * 192 * 4;         // 30,720
    int* tsp2 = (int*)(wsb + o); o += 6 * 4 * 192 * 4;          // 18,432
    int* tsp3 = (int*)(wsb + o); o += 6 * 4 * 192 * 4;
    int* ts4  = (int*)(wsb + o); o += 4 * 4 * 4;                //      64
    o = (o + 15) & ~(size_t)15;
    signed char* xpad = wsb + o; o += 512;                      // -128 halo pad
    signed char* xh = wsb + o; o += (size_t)48 * 48 * 320;
    signed char* a1 = wsb + o; o += (size_t)96 * 96 * 192;
    signed char* a2 = wsb + o; o += (size_t)192 * 192 * 192;
    signed char* a3 = wsb + o; o += (size_t)384 * 384 * 192;

    // convert || packA || pack_w4 || tap_w4 || xpad-fill (independent)
    prep_all<<<372, 256, 0, stream>>>(x, xh, w1, w2, w3, w4,
                                      wpk1, wpk2, wpk3, wpk4,
                                      tsp1, tsp2, tsp3, ts4, (int*)xpad);

    // layer 1: 48x48x320 -> 96x96x192 (R=1: 4-row tiles, 216 blocks, dbuf
    // 1-barrier pipeline)
    deconv_v21<4, 1, true, 0><<<216, 256, 0, stream>>>(
        xh, wpk1, b1, m0, tsp1, 10, relus, dvds, bitsp, xpad, 0, 320, 192, 6, 48, 48,
        /*NB*/6, /*NQX*/3, /*T8*/0, a1);
    // layer 2: 96x96x192 -> 192x192x192 (R=2: 8-row tiles, 432 blocks,
    // single-x+single-b, LDS 31.4KB -> 5 blocks/CU)
    deconv_v21<4, 2, false, 1><<<432, 256, 0, stream>>>(
        a1, wpk2, b2, m1, tsp2, 6, relus, dvds, bitsp, xpad, 1, 192, 192, 6, 96, 96,
        6, 6, 0, a2);
    // layer 3: 192x192x192 -> 384x384x192 (R=2: 8-row tiles, 1728 blocks =
    // 8 XCDs x 36 tiles x 6 nb, single-x+single-b -> 5 blocks/CU)
    deconv_v21<4, 2, false, 2><<<1728, 256, 0, stream>>>(
        a2, wpk3, b3, m2, tsp3, 6, relus, dvds, bitsp, xpad, 2, 192, 192, 6, 192, 192,
        6, 12, 36, a3);
    // layer 4: 384x384x192 -> 3x768x768 (R=2: 576 blocks; f32 NCHW via
    // LDS-staged coalesced stores)
    deconv_final_v21<<<dim3(1, 24, 24), 256, 0, stream>>>(
        a3, wpk4, b4, m3, ts4, dvds, xpad, 192, 384, 384, (float*)d_out);
}

// Round 16
// 196.340 us; speedup vs baseline: 1.0959x; 1.0959x over previous
//
#include <hip/hip_runtime.h>
#include <cmath>

// ---------------------------------------------------------------------------
// g_s: 4x chained conv_transpose2d(k=5,s=2,p=2,op=1) + integer quant epilogue.
// Hermite: sum_j floor((round(w)+j)/split) == round(w) -> one conv per layer.
// Exact i8: weights round(w) in [-127,127]; activations (x-128) in i8; OOB
// halo = -128 so conv_i8 = conv_ref(x) - 128*tapsum[parity][co] (exact i32).
//
// v22 = exact v20 restore (proven band 193.9-198.0us).
//  v21 post-mortem (@215.2, L3 64.2): single-x+single-b at 5 blocks/CU
//  doubled WRITE (27.8->54.4MB = 2x the 28.3MB output) and tripled FETCH —
//  L2 pressure from extra co-resident blocks caused partial-line writeback
//  thrash (i8 32B wave-stores evicted before line completion -> RMW round
//  trips). Also exposed BOTH x and b latency per chunk (v20 drains x(s+1)
//  at iteration s's barrier, so only b is exposed). Verdict: L2-residency,
//  not overlap-partner count, is the binding constraint; occupancy-via-
//  smaller-LDS is net-negative here.
//  Locked-in findings: direct __shared__ only (no LDS pointer args); R=2 for
//  L2/L3/L4; bank-conflict door closed (counter invariant under proven
//  swizzle); dbuf-x + single-b for L2/L3; trunc-fold epilogue; DMA staging;
//  XCD-grouped L3 decode; fused barrier-free prep; L4 LDS-coalesced output.
// ---------------------------------------------------------------------------

typedef int int4v  __attribute__((ext_vector_type(4)));
typedef int int16v __attribute__((ext_vector_type(16)));

#define GLOBAL_AS __attribute__((address_space(1)))
#define LDS_AS    __attribute__((address_space(3)))

// async global->LDS, 16B per lane; LDS dest linear in lane (base+lane*16).
__device__ __forceinline__ void dma16(const signed char* g, signed char* l) {
    __builtin_amdgcn_global_load_lds((const GLOBAL_AS int*)g, (LDS_AS int*)l,
                                     16, 0, 0);
}

// tap id -> (ky,kx). Taps 0-8: EE; 9-14: EO; 15-20: OE; 21-24: OO.
__device__ __forceinline__ void tap_to_k(int t, int& ky, int& kx) {
    if (t < 9)       { int dy = t/3,  dx = t%3;                   ky = 4-2*dy; kx = 4-2*dx; }
    else if (t < 15) { int u = t-9;   int dy = u/2, dx = 1+(u&1);  ky = 4-2*dy; kx = 5-2*dx; }
    else if (t < 21) { int u = t-15;  int dy = 1+u/3, dx = u%3;    ky = 5-2*dy; kx = 4-2*dx; }
    else             { int u = t-21;  int dy = 1+u/2, dx = 1+(u&1); ky = 5-2*dy; kx = 5-2*dx; }
}

// Fused prep (barrier-free; parts independent): bid<180: convert f32 NCHW ->
// i8 NHWC; 180..311: packA (tapsum -> per-qs plain stores, NO atomics);
// 312..365: pack_w4; 366..371: tap_w4 (+ bid==366 hi-half fills xpad).
__global__ __launch_bounds__(256)
void prep_all(const float* __restrict__ x, signed char* __restrict__ xh,
              const float* __restrict__ w1, const float* __restrict__ w2,
              const float* __restrict__ w3, const float* __restrict__ w4,
              signed char* __restrict__ p1, signed char* __restrict__ p2,
              signed char* __restrict__ p3, signed char* __restrict__ p4,
              int* __restrict__ tsp1, int* __restrict__ tsp2,
              int* __restrict__ tsp3, int* __restrict__ t4,
              int* __restrict__ xpadw) {
    __shared__ __align__(16) signed char smem[26112];
    const int bid = blockIdx.x;
    const int tid = threadIdx.x;

    if (bid < 180) {
        float (*t)[65] = (float(*)[65])smem;         // 16,640 B
        const int C = 320, HW = 48 * 48;
        const int p0 = (bid % 36) * 64;
        const int c0 = (bid / 36) * 64;
        const int pL = tid & 63;
        const int r0 = tid >> 6;
        #pragma unroll
        for (int k = 0; k < 16; ++k) {
            int ciL = r0 * 16 + k;
            t[ciL][pL] = x[(size_t)(c0 + ciL) * HW + p0 + pL];
        }
        __syncthreads();
        #pragma unroll
        for (int k = 0; k < 16; ++k) {
            int pL2 = r0 * 16 + k;
            xh[(size_t)(p0 + pL2) * C + c0 + pL] = (signed char)((int)t[pL][pL2] - 128);
        }
    } else if (bid < 312) {
        int u = bid - 180;
        int layer, s;
        if (u < 60)      { layer = 0; s = u; }
        else if (u < 96) { layer = 1; s = u - 60; }
        else             { layer = 2; s = u - 96; }
        const float* w = (layer == 0) ? w1 : (layer == 1) ? w2 : w3;
        signed char* out = (layer == 0) ? p1 : (layer == 1) ? p2 : p3;
        int* tsp = (layer == 0) ? tsp1 : (layer == 1) ? tsp2 : tsp3;
        const int Cout = 192;
        const int qs = s / 6, nb = s % 6;

        signed char* ls = smem;                       // 25,600
        int (*lsum)[32] = (int(*)[32])(smem + 25600); // 512
        if (tid < 128) ((int*)lsum)[tid] = 0;
        __syncthreads();

        #pragma unroll
        for (int k = 0; k < 4; ++k) {
            const int pidx = tid + k * 256;
            const int cil = pidx >> 5;
            const int colp = pidx & 31;
            const int ci = qs * 32 + cil;
            const int cop = nb * 32 + colp;
            const float* wr = w + (size_t)(ci * Cout + cop) * 25;
            const int halfp = cil >> 4, j = cil & 15;
            const int base = (halfp * 32 + colp) * 16 + j;
            int psum[4] = {0, 0, 0, 0};
            #pragma unroll
            for (int tt = 0; tt < 25; ++tt) {
                int ky, kx; tap_to_k(tt, ky, kx);
                float v = rintf(wr[ky * 5 + kx]);
                v = fminf(fmaxf(v, -128.0f), 127.0f);
                int iv = (int)v;
                ls[tt * 1024 + base] = (signed char)iv;
                psum[((ky & 1) << 1) | (kx & 1)] += iv;
            }
            #pragma unroll
            for (int p = 0; p < 4; ++p) atomicAdd(&lsum[p][colp], psum[p]);
        }
        __syncthreads();

        signed char* dst = out + (size_t)s * 25600;
        for (int i = tid; i < 1600; i += 256)
            *(int4v*)&dst[i * 16] = *(const int4v*)&ls[i * 16];
        if (tid < 128) {
            // per-qs partial: written exactly once (this block owns (qs,nb))
            const int p = tid >> 5, colp = tid & 31;
            tsp[(qs * 4 + p) * Cout + nb * 32 + colp] = lsum[p][colp];
        }
    } else if (bid < 366) {
        const int bx = bid - 312;
        #pragma unroll
        for (int k = 0; k < 4; ++k) {
            int idx = bx * 1024 + k * 256 + tid;
            int j    = idx & 15;
            int lane = (idx >> 4) & 63;
            int rem  = idx >> 10;
            int s9   = rem % 9;
            int qs   = rem / 9;
            int colp = lane & 31;
            int cop  = colp & 7;
            int p    = colp >> 3;
            int py = p >> 1, px = p & 1;
            int dy = s9 / 3, dx = s9 % 3;
            int ci = qs * 32 + ((lane >> 5) << 4) + j;
            bool part = (py == 0 || dy >= 1) && (px == 0 || dx >= 1);
            float v = 0.0f;
            if (cop < 3 && part) {
                int ky = py ? 5 - 2 * dy : 4 - 2 * dy;
                int kx = px ? 5 - 2 * dx : 4 - 2 * dx;
                v = rintf(w4[(size_t)(ci * 3 + cop) * 25 + ky * 5 + kx]);
                v = fminf(fmaxf(v, -128.0f), 127.0f);
            }
            p4[idx] = (signed char)(int)v;
        }
    } else {
        if (tid < 128) {
            const int Cin = 192, Cout = 3;
            const int u = (bid - 366) * 2 + (tid >> 6);
            const int lane = tid & 63;
            const int cop = u % Cout, p = u / Cout;
            const int py = p >> 1, px = p & 1;
            const int nky = (5 - py + 1) >> 1;
            const int nkx = (5 - px + 1) >> 1;
            const int ntap = nky * nkx;
            int sacc = 0;
            for (int idx = lane; idx < Cin * ntap; idx += 64) {
                const int ci = idx / ntap;
                const int uu = idx - ci * ntap;
                const int ky = py + 2 * (uu / nkx);
                const int kx = px + 2 * (uu % nkx);
                float v = rintf(w4[(size_t)(ci * Cout + cop) * 25 + ky * 5 + kx]);
                v = fminf(fmaxf(v, -128.0f), 127.0f);
                sacc += (int)v;
            }
            #pragma unroll
            for (int off = 32; off > 0; off >>= 1)
                sacc += __shfl_down(sacc, off, 64);
            if (lane == 0) t4[u] = sacc;
        } else if (bid == 366) {
            // xpad fill (consumed only by later dispatches)
            xpadw[tid - 128] = (int)0x80808080;
        }
    }
}

// Per-role tap tables for parity-split (role0: EE(acc0)+OO(acc1);
// role1: EO(acc0)+OE(acc1)). Verified against the full shift/tap/parity map.
__device__ __forceinline__ constexpr int role_nt(int role, int s9) {
    constexpr int NT0[9] = {1,1,1,1,2,2,1,2,2};
    constexpr int NT1[9] = {0,1,1,1,2,2,1,2,2};
    return role == 0 ? NT0[s9] : NT1[s9];
}
__device__ __forceinline__ constexpr int role_tap(int role, int s9, int u) {
    constexpr int T0[9][2] = {{0,0},{1,0},{2,0},{3,0},{4,21},{5,22},{6,0},{7,23},{8,24}};
    constexpr int T1[9][2] = {{0,0},{9,0},{10,0},{15,0},{11,16},{12,17},{18,0},{13,19},{14,20}};
    return role == 0 ? T0[s9][u] : T1[s9][u];
}
__device__ __forceinline__ constexpr int role_acc(int role, int s9, int u) {
    constexpr int A0[9][2] = {{0,0},{0,0},{0,0},{0,0},{0,1},{0,1},{0,0},{0,1},{0,1}};
    constexpr int A1[9][2] = {{0,0},{0,0},{0,0},{1,0},{0,1},{0,1},{1,0},{0,1},{0,1}};
    return role == 0 ? A0[s9][u] : A1[s9][u];
}

// xs layout: [pix][32B] linear (per-s9 offsets fold into ds_read immediates).
template<int ROLE, int R>
__device__ __forceinline__ void compute_role(const signed char* xsb, const signed char* bsb,
                                             int16v (&acc)[R][2], const int (&p0)[R],
                                             int half, int lane) {
    #pragma unroll
    for (int s9 = 0; s9 < 9; ++s9) {
        if (role_nt(ROLE, s9) == 0) continue;
        const int dy = s9 / 3, dx = s9 % 3;
        int4v a[R];
        #pragma unroll
        for (int r = 0; r < R; ++r)
            a[r] = *(const int4v*)&xsb[(p0[r] + dy * 18 + dx) * 32 + half * 16];
        #pragma unroll
        for (int u = 0; u < 2; ++u) {
            if (u < role_nt(ROLE, s9)) {
                int4v b = *(const int4v*)&bsb[role_tap(ROLE, s9, u) * 1024 + lane * 16];
                const int ai = role_acc(ROLE, s9, u);
                #pragma unroll
                for (int r = 0; r < R; ++r)
                    acc[r][ai] = __builtin_amdgcn_mfma_i32_32x32x32_i8(a[r], b, acc[r][ai], 0, 0, 0);
            }
        }
    }
}

// Layers 1-3 (v17 structure: template __global__, DIRECT __shared__ arrays so
// LDS offsets fold into ds_read immediates): MW waves = MW/2 pairs x R
// subtiles. x DMA dbuf; b dbuf (BDBUF, 1 barrier/chunk) or single (2/chunk).
// T8>0: XCD-grouped decode. tapsum = sum of QS per-qs partials.
template<int MW, int R, bool BDBUF, int TAG>
__global__ __launch_bounds__(MW * 64, 4)
void deconv_v22(const signed char* __restrict__ xin, const signed char* __restrict__ wpk,
                const float* __restrict__ bias, const float* __restrict__ muls,
                const int* __restrict__ tsp, int QS,
                const float* __restrict__ relus, const int* __restrict__ dvds,
                const int* __restrict__ bitsp, const signed char* __restrict__ xpad,
                int layer, int Cin, int Cout, int NT, int Hq, int Wq,
                int NB, int NQX, int T8,
                signed char* __restrict__ outp) {
    constexpr int PAIRS = MW / 2;
    constexpr int QROWS = PAIRS * R * 2;
    constexpr int NROW = QROWS + 2;
    constexpr int NPIX = NROW * 18;
    constexpr int THREADS = MW * 64;
    constexpr int XC = NPIX * 2;
    constexpr int XI = (XC + THREADS - 1) / THREADS;
    constexpr int BC = 1600;
    constexpr int BI = (BC + THREADS - 1) / THREADS;
    constexpr int NBS = BDBUF ? 2 : 1;

    __shared__ __align__(16) signed char xs[2][NPIX * 32];
    __shared__ __align__(16) signed char bs[NBS][25600];

    const int tid  = threadIdx.x;
    const int lane = tid & 63;
    const int wid  = tid >> 6;
    const int pairId = wid >> 1;
    const int role   = wid & 1;

    int nb, qx, qy;
    {
        const int bi = blockIdx.x;
        if (T8 > 0) {
            const int xcd = bi & 7, j = bi >> 3;
            const int tl = j / NB, n = j - tl * NB;
            const int tile = xcd * T8 + tl;
            nb = n; qx = tile % NQX; qy = tile / NQX;
        } else {
            nb = bi % NB;
            const int s = bi / NB;
            qx = s % NQX; qy = s / NQX;
        }
    }
    const int qx0 = qx * 16;
    const int qy0 = qy * QROWS;
    const int n0  = nb * 32;

    int16v acc[R][2];
    #pragma unroll
    for (int r = 0; r < R; ++r)
        #pragma unroll
        for (int p = 0; p < 2; ++p)
            #pragma unroll
            for (int e = 0; e < 16; ++e) acc[r][p][e] = 0;

    const int half   = lane >> 5;
    const int rowbit = (lane >> 4) & 1;
    const int col    = lane & 15;
    int p0[R];
    #pragma unroll
    for (int r = 0; r < R; ++r)
        p0[r] = ((pairId * R + r) * 2 + rowbit) * 18 + col;

    // per-slot DMA source base (ck added later; OOB -> xpad, +ck stays in pad)
    const signed char* xsrc[XI];
    #pragma unroll
    for (int t = 0; t < XI; ++t) {
        int i = tid + t * THREADS;
        xsrc[t] = xpad;
        if (i < XC) {
            int pix = i >> 1, g = i & 1;
            int rr = pix / 18, cc = pix - rr * 18;
            int y = qy0 - 1 + rr, xx = qx0 - 1 + cc;
            bool ok = (unsigned)y < (unsigned)Hq && (unsigned)xx < (unsigned)Wq;
            xsrc[t] = ok ? (xin + ((size_t)y * Wq + xx) * Cin + g * 16)
                         : (xpad + g * 16);
        }
    }

    auto dma_x = [&](int ck, int b) {
        #pragma unroll
        for (int t = 0; t < XI; ++t) {
            int i = tid + t * THREADS;
            if (i < XC) dma16(xsrc[t] + ck, &xs[b][i * 16]);
        }
    };
    auto dma_b = [&](int cs, int b) {
        const signed char* ws = wpk + (size_t)(cs * NT + nb) * 25600;
        #pragma unroll
        for (int t = 0; t < BI; ++t) {
            int i = tid + t * THREADS;
            if (i < BC) dma16(ws + (size_t)i * 16, &bs[b][i * 16]);
        }
    };

    dma_x(0, 0);
    if (BDBUF) dma_b(0, 0);
    for (int ck = 0, s = 0; ck < Cin; ck += 32, ++s) {
        const int cb = s & 1;
        if (BDBUF) {
            __syncthreads();   // vmcnt(0) drain -> DMA(cur) landed; all waves
                               // done reading bufs before next overwrite
            if (ck + 32 < Cin) {
                dma_x((s + 1) * 32, cb ^ 1);
                dma_b(s + 1, cb ^ 1);
            }
            if (role == 0) compute_role<0, R>(xs[cb], bs[cb & (NBS - 1)], acc, p0, half, lane);
            else           compute_role<1, R>(xs[cb], bs[cb & (NBS - 1)], acc, p0, half, lane);
        } else {
            __syncthreads();               // A: prev compute done reading bs/xs[cb^1]
            dma_b(s, 0);                   // overwrite single b buffer
            if (ck + 32 < Cin) dma_x((s + 1) * 32, cb ^ 1);
            __syncthreads();               // B: vmcnt(0) -> b (and x-next) landed
            if (role == 0) compute_role<0, R>(xs[cb], bs[0], acc, p0, half, lane);
            else           compute_role<1, R>(xs[cb], bs[0], acc, p0, half, lane);
        }
    }

    // ----- quant epilogue (exact fp32 op sequence; proven absmax 0.0) --------
    const int dv = dvds[layer];
    float add1 = ldexpf(1.0f, dv - 10);
    float inv1 = ldexpf(1.0f, -(dv - 9));
    const float relu = relus[layer];
    const int sk = (layer == 1) ? 4 : 3;
    const float bitsv = ldexpf(1.0f, bitsp[0]) - 1.0f;
    float clp, scl;
    {
        #pragma clang fp contract(off)
        clp = rintf(bitsv / relu * 33554432.0f);
        scl = floorf((relu + ldexpf(1.0f, sk - 1)) * ldexpf(1.0f, -sk));
    }
    float add2 = ldexpf(1.0f, 24 - sk);
    float inv2 = ldexpf(1.0f, -(25 - sk));

    const int co = n0 + (lane & 31);
    float bq = rintf(bias[co]);
    float mm = muls[co];
    // wave's two parities: role0 -> {EE=0, OO=3}; role1 -> {EO=1, OE=2}
    int pmap[2];
    pmap[0] = role == 0 ? 0 : 1;
    pmap[1] = role == 0 ? 3 : 2;
    // tapsum = sum of QS per-qs partials (exact integer adds; no atomics)
    int fullp[2] = {0, 0};
    for (int q = 0; q < QS; ++q) {
        fullp[0] += tsp[(q * 4 + pmap[0]) * Cout + co];
        fullp[1] += tsp[(q * 4 + pmap[1]) * Cout + co];
    }

    const int Wout = Wq * 2;

    #pragma unroll
    for (int r = 0; r < R; ++r) {
        #pragma unroll
        for (int a = 0; a < 2; ++a) {
            const int p = pmap[a];
            const int py = p >> 1, px = p & 1;
            #pragma unroll
            for (int reg = 0; reg < 16; ++reg) {
                const int mrow = (reg & 3) + 8 * (reg >> 2) + 4 * (lane >> 5);
                const int qy2 = qy0 + (pairId * R + r) * 2 + (mrow >> 4);
                const int qx2 = qx0 + (mrow & 15);
                float v = (float)(acc[r][a][reg] + 128 * fullp[a]);
                int iv;
                {
                    #pragma clang fp contract(off)
                    v = (v + bq) * mm;
                    v = floorf((v + add1) * inv1);
                    v = fminf(fmaxf(v, 0.0f), clp);
                    iv = (int)((v * scl + add2) * inv2);   // trunc == floor (v>=0)
                }
                const int oy = 2 * qy2 + py, ox = 2 * qx2 + px;
                outp[((size_t)oy * Wout + ox) * Cout + co] = (signed char)(iv - 128);
            }
        }
    }
}

// Final layer: N = (parity,co) columns, 1 MFMA per shift, R=2, MW=4 (576
// blocks); x+b DMA double-buffered, 1 barrier/chunk; output staged in LDS
// (obuf aliases dead xs/bs after K-loop) then stored as 128B-contiguous rows.
__global__ __launch_bounds__(256, 4)
void deconv_final_v22(const signed char* __restrict__ xin, const signed char* __restrict__ wpk,
                      const float* __restrict__ bias, const float* __restrict__ muls,
                      const int* __restrict__ tsum, const int* __restrict__ dvds,
                      const signed char* __restrict__ xpad,
                      int Cin, int Hq, int Wq, float* __restrict__ outp) {
    constexpr int R = 2, MW = 4;
    constexpr int QROWS = MW * R * 2;      // 16
    constexpr int NROW = QROWS + 2;        // 18
    constexpr int NPIX = NROW * 18;        // 324
    constexpr int THREADS = 256;
    constexpr int XC = NPIX * 2;           // 648
    constexpr int XI = (XC + THREADS - 1) / THREADS;   // 3
    constexpr int BC = 576;
    constexpr int BI = (BC + THREADS - 1) / THREADS;   // 3
    constexpr int XBUF = NPIX * 32;        // 10368

    // xs/bs during K-loop; obuf (3x32x32 f32 = 12,288B) aliases them after.
    __shared__ __align__(16) signed char smem[2 * XBUF + 2 * 9216]; // 39,168
    signed char (*xs)[XBUF] = (signed char(*)[XBUF])smem;
    signed char (*bs)[9216] = (signed char(*)[9216])(smem + 2 * XBUF);
    float* obuf = (float*)smem;

    const int tid  = threadIdx.x;
    const int lane = tid & 63;
    const int wid  = tid >> 6;
    const int qx0  = blockIdx.y * 16;
    const int qy0  = blockIdx.z * QROWS;

    int16v acc[R];
    #pragma unroll
    for (int r = 0; r < R; ++r)
        #pragma unroll
        for (int e = 0; e < 16; ++e) acc[r][e] = 0;

    const int half   = lane >> 5;
    const int rowbit = (lane >> 4) & 1;
    const int col    = lane & 15;
    int p0[R];
    #pragma unroll
    for (int r = 0; r < R; ++r)
        p0[r] = ((wid * R + r) * 2 + rowbit) * 18 + col;

    const signed char* xsrc[XI];
    #pragma unroll
    for (int t = 0; t < XI; ++t) {
        int i = tid + t * THREADS;
        xsrc[t] = xpad;
        if (i < XC) {
            int pix = i >> 1, g = i & 1;
            int rr = pix / 18, cc = pix - rr * 18;
            int y = qy0 - 1 + rr, xx = qx0 - 1 + cc;
            bool ok = (unsigned)y < (unsigned)Hq && (unsigned)xx < (unsigned)Wq;
            xsrc[t] = ok ? (xin + ((size_t)y * Wq + xx) * Cin + g * 16)
                         : (xpad + g * 16);
        }
    }

    auto dma_x = [&](int ck, int b) {
        #pragma unroll
        for (int t = 0; t < XI; ++t) {
            int i = tid + t * THREADS;
            if (i < XC) dma16(xsrc[t] + ck, &xs[b][i * 16]);
        }
    };
    auto dma_b = [&](int cs, int b) {
        const signed char* ws = wpk + (size_t)cs * 9216;
        #pragma unroll
        for (int t = 0; t < BI; ++t) {
            int i = tid + t * THREADS;
            if (i < BC) dma16(ws + (size_t)i * 16, &bs[b][i * 16]);
        }
    };

    dma_x(0, 0);
    dma_b(0, 0);
    for (int ck = 0; ck < Cin; ck += 32) {
        const int cb = (ck >> 5) & 1;
        __syncthreads();
        if (ck + 32 < Cin) {
            dma_x(ck + 32, cb ^ 1);
            dma_b((ck >> 5) + 1, cb ^ 1);
        }
        #pragma unroll
        for (int s9 = 0; s9 < 9; ++s9) {
            const int dy = s9 / 3, dx = s9 % 3;
            int4v b = *(const int4v*)&bs[cb][s9 * 1024 + lane * 16];
            #pragma unroll
            for (int r = 0; r < R; ++r) {
                int4v a = *(const int4v*)&xs[cb][(p0[r] + dy * 18 + dx) * 32 + half * 16];
                acc[r] = __builtin_amdgcn_mfma_i32_32x32x32_i8(a, b, acc[r], 0, 0, 0);
            }
        }
    }

    const int dv = dvds[3];
    const float add1 = ldexpf(1.0f, dv - 9);
    const float inv1 = ldexpf(1.0f, -(dv - 8));

    const int coln = lane & 31;
    const int co = coln & 7;
    const int p  = coln >> 3;
    const int py = p >> 1, px = p & 1;
    const bool valid = (co < 3);
    float bq = 0.f, mm = 0.f;
    int fp = 0;
    if (valid) { bq = rintf(bias[co]); mm = muls[co]; fp = tsum[p * 3 + co]; }

    __syncthreads();   // all waves done reading xs/bs (obuf aliases them)

    // epilogue -> obuf[co][ly][lx] (local 32x32 px block per co plane)
    #pragma unroll
    for (int r = 0; r < R; ++r) {
        #pragma unroll
        for (int reg = 0; reg < 16; ++reg) {
            const int mrow = (reg & 3) + 8 * (reg >> 2) + 4 * (lane >> 5);
            const int lq_y = (wid * R + r) * 2 + (mrow >> 4);   // 0..15
            const int lq_x = mrow & 15;                          // 0..15
            float v = (float)(acc[r][reg] + 128 * fp);
            {
                #pragma clang fp contract(off)
                v = (v + bq) * mm;
                v = floorf((v + add1) * inv1);   // keep floorf: v may be negative
                v = v / 255.0f;
            }
            if (valid) {
                const int ly = 2 * lq_y + py, lx = 2 * lq_x + px;
                obuf[co * 1024 + ly * 32 + lx] = v;
            }
        }
    }
    __syncthreads();

    // coalesced store: 3072 floats = 96 rows of 32 floats (128B contiguous)
    const int Wout = Wq * 2, Hout = Hq * 2;
    const int oyb = qy0 * 2, oxb = qx0 * 2;
    #pragma unroll
    for (int k = 0; k < 12; ++k) {
        const int idx = tid + k * 256;
        const int c  = idx >> 10;
        const int rem = idx & 1023;
        const int ly = rem >> 5, lx = rem & 31;
        outp[((size_t)c * Hout + oyb + ly) * Wout + oxb + lx] = obuf[idx];
    }
}

extern "C" void kernel_launch(void* const* d_in, const int* in_sizes, int n_in,
                              void* d_out, int out_size, void* d_ws, size_t ws_size,
                              hipStream_t stream) {
    const float* x  = (const float*)d_in[0];
    const float* w1 = (const float*)d_in[1];
    const float* b1 = (const float*)d_in[2];
    const float* w2 = (const float*)d_in[3];
    const float* b2 = (const float*)d_in[4];
    const float* w3 = (const float*)d_in[5];
    const float* b3 = (const float*)d_in[6];
    const float* w4 = (const float*)d_in[7];
    const float* b4 = (const float*)d_in[8];
    const float* m0 = (const float*)d_in[9];
    const float* m1 = (const float*)d_in[10];
    const float* m2 = (const float*)d_in[11];
    const float* m3 = (const float*)d_in[12];
    const float* relus = (const float*)d_in[13];
    const int* dvds = (const int*)d_in[14];
    const int* bitsp = (const int*)d_in[15];

    signed char* wsb = (signed char*)d_ws;
    size_t o = 0;
    signed char* wpk1 = wsb + o; o += (size_t)10 * 6 * 25600;   // 1,536,000
    signed char* wpk2 = wsb + o; o += (size_t)6 * 6 * 25600;    //   921,600
    signed char* wpk3 = wsb + o; o += (size_t)6 * 6 * 25600;
    signed char* wpk4 = wsb + o; o += (size_t)6 * 9216;         //    55,296
    // per-qs tapsum partials (plain stores, no zeroing needed)
    int* tsp1 = (int*)(wsb + o); o += 10 * 4 * 192 * 4;         // 30,720
    int* tsp2 = (int*)(wsb + o); o += 6 * 4 * 192 * 4;          // 18,432
    int* tsp3 = (int*)(wsb + o); o += 6 * 4 * 192 * 4;
    int* ts4  = (int*)(wsb + o); o += 4 * 4 * 4;                //      64
    o = (o + 15) & ~(size_t)15;
    signed char* xpad = wsb + o; o += 512;                      // -128 halo pad
    signed char* xh = wsb + o; o += (size_t)48 * 48 * 320;
    signed char* a1 = wsb + o; o += (size_t)96 * 96 * 192;
    signed char* a2 = wsb + o; o += (size_t)192 * 192 * 192;
    signed char* a3 = wsb + o; o += (size_t)384 * 384 * 192;

    // convert || packA || pack_w4 || tap_w4 || xpad-fill (independent)
    prep_all<<<372, 256, 0, stream>>>(x, xh, w1, w2, w3, w4,
                                      wpk1, wpk2, wpk3, wpk4,
                                      tsp1, tsp2, tsp3, ts4, (int*)xpad);

    // layer 1: 48x48x320 -> 96x96x192 (R=1: 4-row tiles, 216 blocks, dbuf-b)
    deconv_v22<4, 1, true, 0><<<216, 256, 0, stream>>>(
        xh, wpk1, b1, m0, tsp1, 10, relus, dvds, bitsp, xpad, 0, 320, 192, 6, 48, 48,
        /*NB*/6, /*NQX*/3, /*T8*/0, a1);
    // layer 2: 96x96x192 -> 192x192x192 (R=2: 8-row tiles, 432 blocks, single-b)
    deconv_v22<4, 2, false, 1><<<432, 256, 0, stream>>>(
        a1, wpk2, b2, m1, tsp2, 6, relus, dvds, bitsp, xpad, 1, 192, 192, 6, 96, 96,
        6, 6, 0, a2);
    // layer 3: 192x192x192 -> 384x384x192 (R=2: 8-row tiles, 1728 blocks =
    // 8 XCDs x 36 tiles x 6 nb, single-b; ~1.9MB/XCD L2-resident)
    deconv_v22<4, 2, false, 2><<<1728, 256, 0, stream>>>(
        a2, wpk3, b3, m2, tsp3, 6, relus, dvds, bitsp, xpad, 2, 192, 192, 6, 192, 192,
        6, 12, 36, a3);
    // layer 4: 384x384x192 -> 3x768x768 (R=2: 576 blocks; f32 NCHW via
    // LDS-staged coalesced stores)
    deconv_final_v22<<<dim3(1, 24, 24), 256, 0, stream>>>(
        a3, wpk4, b4, m3, ts4, dvds, xpad, 192, 384, 384, (float*)d_out);
}

// Round 17
// 193.120 us; speedup vs baseline: 1.1142x; 1.0167x over previous
//
#include <hip/hip_runtime.h>
#include <cmath>

// ---------------------------------------------------------------------------
// g_s: 4x chained conv_transpose2d(k=5,s=2,p=2,op=1) + integer quant epilogue.
// Hermite: sum_j floor((round(w)+j)/split) == round(w) -> one conv per layer.
// Exact i8: weights round(w) in [-127,127]; activations (x-128) in i8; OOB
// halo = -128 so conv_i8 = conv_ref(x) - 128*tapsum[parity][co] (exact i32).
//
// v23 = v22 (proven band 194-198us; L3 50.1-50.4 across 5 runs) + T5:
//  s_setprio(1)/(0) around the compute phase of all deconv kernels.
//  Mechanism (structure-conditional per catalog): deconv blocks are
//  INDEPENDENT barrier domains at ~3.4 blocks/CU, so co-resident waves sit
//  at different phases (DMA-issue vs MFMA-burst vs epilogue-VALU); priority
//  lets MFMA-entering waves win issue arbitration (attn-like m191 regime,
//  not the lockstep m190 null). 2-instruction change, zero correctness risk.
//  If within noise: catalog exhausted -> declare structural plateau.
//  Locked-in: direct __shared__ (no LDS ptr args); R=2 for L2/L3/L4; dbuf-x +
//  single-b L2/L3; dbuf both L1/L4; trunc-fold epilogue; DMA staging;
//  XCD-grouped L3; fused barrier-free prep; L4 LDS-coalesced output.
// ---------------------------------------------------------------------------

typedef int int4v  __attribute__((ext_vector_type(4)));
typedef int int16v __attribute__((ext_vector_type(16)));

#define GLOBAL_AS __attribute__((address_space(1)))
#define LDS_AS    __attribute__((address_space(3)))

// async global->LDS, 16B per lane; LDS dest linear in lane (base+lane*16).
__device__ __forceinline__ void dma16(const signed char* g, signed char* l) {
    __builtin_amdgcn_global_load_lds((const GLOBAL_AS int*)g, (LDS_AS int*)l,
                                     16, 0, 0);
}

// tap id -> (ky,kx). Taps 0-8: EE; 9-14: EO; 15-20: OE; 21-24: OO.
__device__ __forceinline__ void tap_to_k(int t, int& ky, int& kx) {
    if (t < 9)       { int dy = t/3,  dx = t%3;                   ky = 4-2*dy; kx = 4-2*dx; }
    else if (t < 15) { int u = t-9;   int dy = u/2, dx = 1+(u&1);  ky = 4-2*dy; kx = 5-2*dx; }
    else if (t < 21) { int u = t-15;  int dy = 1+u/3, dx = u%3;    ky = 5-2*dy; kx = 4-2*dx; }
    else             { int u = t-21;  int dy = 1+u/2, dx = 1+(u&1); ky = 5-2*dy; kx = 5-2*dx; }
}

// Fused prep (barrier-free; parts independent): bid<180: convert f32 NCHW ->
// i8 NHWC; 180..311: packA (tapsum -> per-qs plain stores, NO atomics);
// 312..365: pack_w4; 366..371: tap_w4 (+ bid==366 hi-half fills xpad).
__global__ __launch_bounds__(256)
void prep_all(const float* __restrict__ x, signed char* __restrict__ xh,
              const float* __restrict__ w1, const float* __restrict__ w2,
              const float* __restrict__ w3, const float* __restrict__ w4,
              signed char* __restrict__ p1, signed char* __restrict__ p2,
              signed char* __restrict__ p3, signed char* __restrict__ p4,
              int* __restrict__ tsp1, int* __restrict__ tsp2,
              int* __restrict__ tsp3, int* __restrict__ t4,
              int* __restrict__ xpadw) {
    __shared__ __align__(16) signed char smem[26112];
    const int bid = blockIdx.x;
    const int tid = threadIdx.x;

    if (bid < 180) {
        float (*t)[65] = (float(*)[65])smem;         // 16,640 B
        const int C = 320, HW = 48 * 48;
        const int p0 = (bid % 36) * 64;
        const int c0 = (bid / 36) * 64;
        const int pL = tid & 63;
        const int r0 = tid >> 6;
        #pragma unroll
        for (int k = 0; k < 16; ++k) {
            int ciL = r0 * 16 + k;
            t[ciL][pL] = x[(size_t)(c0 + ciL) * HW + p0 + pL];
        }
        __syncthreads();
        #pragma unroll
        for (int k = 0; k < 16; ++k) {
            int pL2 = r0 * 16 + k;
            xh[(size_t)(p0 + pL2) * C + c0 + pL] = (signed char)((int)t[pL][pL2] - 128);
        }
    } else if (bid < 312) {
        int u = bid - 180;
        int layer, s;
        if (u < 60)      { layer = 0; s = u; }
        else if (u < 96) { layer = 1; s = u - 60; }
        else             { layer = 2; s = u - 96; }
        const float* w = (layer == 0) ? w1 : (layer == 1) ? w2 : w3;
        signed char* out = (layer == 0) ? p1 : (layer == 1) ? p2 : p3;
        int* tsp = (layer == 0) ? tsp1 : (layer == 1) ? tsp2 : tsp3;
        const int Cout = 192;
        const int qs = s / 6, nb = s % 6;

        signed char* ls = smem;                       // 25,600
        int (*lsum)[32] = (int(*)[32])(smem + 25600); // 512
        if (tid < 128) ((int*)lsum)[tid] = 0;
        __syncthreads();

        #pragma unroll
        for (int k = 0; k < 4; ++k) {
            const int pidx = tid + k * 256;
            const int cil = pidx >> 5;
            const int colp = pidx & 31;
            const int ci = qs * 32 + cil;
            const int cop = nb * 32 + colp;
            const float* wr = w + (size_t)(ci * Cout + cop) * 25;
            const int halfp = cil >> 4, j = cil & 15;
            const int base = (halfp * 32 + colp) * 16 + j;
            int psum[4] = {0, 0, 0, 0};
            #pragma unroll
            for (int tt = 0; tt < 25; ++tt) {
                int ky, kx; tap_to_k(tt, ky, kx);
                float v = rintf(wr[ky * 5 + kx]);
                v = fminf(fmaxf(v, -128.0f), 127.0f);
                int iv = (int)v;
                ls[tt * 1024 + base] = (signed char)iv;
                psum[((ky & 1) << 1) | (kx & 1)] += iv;
            }
            #pragma unroll
            for (int p = 0; p < 4; ++p) atomicAdd(&lsum[p][colp], psum[p]);
        }
        __syncthreads();

        signed char* dst = out + (size_t)s * 25600;
        for (int i = tid; i < 1600; i += 256)
            *(int4v*)&dst[i * 16] = *(const int4v*)&ls[i * 16];
        if (tid < 128) {
            // per-qs partial: written exactly once (this block owns (qs,nb))
            const int p = tid >> 5, colp = tid & 31;
            tsp[(qs * 4 + p) * Cout + nb * 32 + colp] = lsum[p][colp];
        }
    } else if (bid < 366) {
        const int bx = bid - 312;
        #pragma unroll
        for (int k = 0; k < 4; ++k) {
            int idx = bx * 1024 + k * 256 + tid;
            int j    = idx & 15;
            int lane = (idx >> 4) & 63;
            int rem  = idx >> 10;
            int s9   = rem % 9;
            int qs   = rem / 9;
            int colp = lane & 31;
            int cop  = colp & 7;
            int p    = colp >> 3;
            int py = p >> 1, px = p & 1;
            int dy = s9 / 3, dx = s9 % 3;
            int ci = qs * 32 + ((lane >> 5) << 4) + j;
            bool part = (py == 0 || dy >= 1) && (px == 0 || dx >= 1);
            float v = 0.0f;
            if (cop < 3 && part) {
                int ky = py ? 5 - 2 * dy : 4 - 2 * dy;
                int kx = px ? 5 - 2 * dx : 4 - 2 * dx;
                v = rintf(w4[(size_t)(ci * 3 + cop) * 25 + ky * 5 + kx]);
                v = fminf(fmaxf(v, -128.0f), 127.0f);
            }
            p4[idx] = (signed char)(int)v;
        }
    } else {
        if (tid < 128) {
            const int Cin = 192, Cout = 3;
            const int u = (bid - 366) * 2 + (tid >> 6);
            const int lane = tid & 63;
            const int cop = u % Cout, p = u / Cout;
            const int py = p >> 1, px = p & 1;
            const int nky = (5 - py + 1) >> 1;
            const int nkx = (5 - px + 1) >> 1;
            const int ntap = nky * nkx;
            int sacc = 0;
            for (int idx = lane; idx < Cin * ntap; idx += 64) {
                const int ci = idx / ntap;
                const int uu = idx - ci * ntap;
                const int ky = py + 2 * (uu / nkx);
                const int kx = px + 2 * (uu % nkx);
                float v = rintf(w4[(size_t)(ci * Cout + cop) * 25 + ky * 5 + kx]);
                v = fminf(fmaxf(v, -128.0f), 127.0f);
                sacc += (int)v;
            }
            #pragma unroll
            for (int off = 32; off > 0; off >>= 1)
                sacc += __shfl_down(sacc, off, 64);
            if (lane == 0) t4[u] = sacc;
        } else if (bid == 366) {
            // xpad fill (consumed only by later dispatches)
            xpadw[tid - 128] = (int)0x80808080;
        }
    }
}

// Per-role tap tables for parity-split (role0: EE(acc0)+OO(acc1);
// role1: EO(acc0)+OE(acc1)). Verified against the full shift/tap/parity map.
__device__ __forceinline__ constexpr int role_nt(int role, int s9) {
    constexpr int NT0[9] = {1,1,1,1,2,2,1,2,2};
    constexpr int NT1[9] = {0,1,1,1,2,2,1,2,2};
    return role == 0 ? NT0[s9] : NT1[s9];
}
__device__ __forceinline__ constexpr int role_tap(int role, int s9, int u) {
    constexpr int T0[9][2] = {{0,0},{1,0},{2,0},{3,0},{4,21},{5,22},{6,0},{7,23},{8,24}};
    constexpr int T1[9][2] = {{0,0},{9,0},{10,0},{15,0},{11,16},{12,17},{18,0},{13,19},{14,20}};
    return role == 0 ? T0[s9][u] : T1[s9][u];
}
__device__ __forceinline__ constexpr int role_acc(int role, int s9, int u) {
    constexpr int A0[9][2] = {{0,0},{0,0},{0,0},{0,0},{0,1},{0,1},{0,0},{0,1},{0,1}};
    constexpr int A1[9][2] = {{0,0},{0,0},{0,0},{1,0},{0,1},{0,1},{1,0},{0,1},{0,1}};
    return role == 0 ? A0[s9][u] : A1[s9][u];
}

// xs layout: [pix][32B] linear (per-s9 offsets fold into ds_read immediates).
template<int ROLE, int R>
__device__ __forceinline__ void compute_role(const signed char* xsb, const signed char* bsb,
                                             int16v (&acc)[R][2], const int (&p0)[R],
                                             int half, int lane) {
    #pragma unroll
    for (int s9 = 0; s9 < 9; ++s9) {
        if (role_nt(ROLE, s9) == 0) continue;
        const int dy = s9 / 3, dx = s9 % 3;
        int4v a[R];
        #pragma unroll
        for (int r = 0; r < R; ++r)
            a[r] = *(const int4v*)&xsb[(p0[r] + dy * 18 + dx) * 32 + half * 16];
        #pragma unroll
        for (int u = 0; u < 2; ++u) {
            if (u < role_nt(ROLE, s9)) {
                int4v b = *(const int4v*)&bsb[role_tap(ROLE, s9, u) * 1024 + lane * 16];
                const int ai = role_acc(ROLE, s9, u);
                #pragma unroll
                for (int r = 0; r < R; ++r)
                    acc[r][ai] = __builtin_amdgcn_mfma_i32_32x32x32_i8(a[r], b, acc[r][ai], 0, 0, 0);
            }
        }
    }
}

// Layers 1-3 (v17 structure: template __global__, DIRECT __shared__ arrays so
// LDS offsets fold into ds_read immediates): MW waves = MW/2 pairs x R
// subtiles. x DMA dbuf; b dbuf (BDBUF, 1 barrier/chunk) or single (2/chunk).
// T8>0: XCD-grouped decode. tapsum = sum of QS per-qs partials.
// T5: setprio(1) around the compute phase (independent-block arbitration).
template<int MW, int R, bool BDBUF, int TAG>
__global__ __launch_bounds__(MW * 64, 4)
void deconv_v23(const signed char* __restrict__ xin, const signed char* __restrict__ wpk,
                const float* __restrict__ bias, const float* __restrict__ muls,
                const int* __restrict__ tsp, int QS,
                const float* __restrict__ relus, const int* __restrict__ dvds,
                const int* __restrict__ bitsp, const signed char* __restrict__ xpad,
                int layer, int Cin, int Cout, int NT, int Hq, int Wq,
                int NB, int NQX, int T8,
                signed char* __restrict__ outp) {
    constexpr int PAIRS = MW / 2;
    constexpr int QROWS = PAIRS * R * 2;
    constexpr int NROW = QROWS + 2;
    constexpr int NPIX = NROW * 18;
    constexpr int THREADS = MW * 64;
    constexpr int XC = NPIX * 2;
    constexpr int XI = (XC + THREADS - 1) / THREADS;
    constexpr int BC = 1600;
    constexpr int BI = (BC + THREADS - 1) / THREADS;
    constexpr int NBS = BDBUF ? 2 : 1;

    __shared__ __align__(16) signed char xs[2][NPIX * 32];
    __shared__ __align__(16) signed char bs[NBS][25600];

    const int tid  = threadIdx.x;
    const int lane = tid & 63;
    const int wid  = tid >> 6;
    const int pairId = wid >> 1;
    const int role   = wid & 1;

    int nb, qx, qy;
    {
        const int bi = blockIdx.x;
        if (T8 > 0) {
            const int xcd = bi & 7, j = bi >> 3;
            const int tl = j / NB, n = j - tl * NB;
            const int tile = xcd * T8 + tl;
            nb = n; qx = tile % NQX; qy = tile / NQX;
        } else {
            nb = bi % NB;
            const int s = bi / NB;
            qx = s % NQX; qy = s / NQX;
        }
    }
    const int qx0 = qx * 16;
    const int qy0 = qy * QROWS;
    const int n0  = nb * 32;

    int16v acc[R][2];
    #pragma unroll
    for (int r = 0; r < R; ++r)
        #pragma unroll
        for (int p = 0; p < 2; ++p)
            #pragma unroll
            for (int e = 0; e < 16; ++e) acc[r][p][e] = 0;

    const int half   = lane >> 5;
    const int rowbit = (lane >> 4) & 1;
    const int col    = lane & 15;
    int p0[R];
    #pragma unroll
    for (int r = 0; r < R; ++r)
        p0[r] = ((pairId * R + r) * 2 + rowbit) * 18 + col;

    // per-slot DMA source base (ck added later; OOB -> xpad, +ck stays in pad)
    const signed char* xsrc[XI];
    #pragma unroll
    for (int t = 0; t < XI; ++t) {
        int i = tid + t * THREADS;
        xsrc[t] = xpad;
        if (i < XC) {
            int pix = i >> 1, g = i & 1;
            int rr = pix / 18, cc = pix - rr * 18;
            int y = qy0 - 1 + rr, xx = qx0 - 1 + cc;
            bool ok = (unsigned)y < (unsigned)Hq && (unsigned)xx < (unsigned)Wq;
            xsrc[t] = ok ? (xin + ((size_t)y * Wq + xx) * Cin + g * 16)
                         : (xpad + g * 16);
        }
    }

    auto dma_x = [&](int ck, int b) {
        #pragma unroll
        for (int t = 0; t < XI; ++t) {
            int i = tid + t * THREADS;
            if (i < XC) dma16(xsrc[t] + ck, &xs[b][i * 16]);
        }
    };
    auto dma_b = [&](int cs, int b) {
        const signed char* ws = wpk + (size_t)(cs * NT + nb) * 25600;
        #pragma unroll
        for (int t = 0; t < BI; ++t) {
            int i = tid + t * THREADS;
            if (i < BC) dma16(ws + (size_t)i * 16, &bs[b][i * 16]);
        }
    };

    dma_x(0, 0);
    if (BDBUF) dma_b(0, 0);
    for (int ck = 0, s = 0; ck < Cin; ck += 32, ++s) {
        const int cb = s & 1;
        if (BDBUF) {
            __syncthreads();   // vmcnt(0) drain -> DMA(cur) landed; all waves
                               // done reading bufs before next overwrite
            if (ck + 32 < Cin) {
                dma_x((s + 1) * 32, cb ^ 1);
                dma_b(s + 1, cb ^ 1);
            }
            __builtin_amdgcn_s_setprio(1);
            if (role == 0) compute_role<0, R>(xs[cb], bs[cb & (NBS - 1)], acc, p0, half, lane);
            else           compute_role<1, R>(xs[cb], bs[cb & (NBS - 1)], acc, p0, half, lane);
            __builtin_amdgcn_s_setprio(0);
        } else {
            __syncthreads();               // A: prev compute done reading bs/xs[cb^1]
            dma_b(s, 0);                   // overwrite single b buffer
            if (ck + 32 < Cin) dma_x((s + 1) * 32, cb ^ 1);
            __syncthreads();               // B: vmcnt(0) -> b (and x-next) landed
            __builtin_amdgcn_s_setprio(1);
            if (role == 0) compute_role<0, R>(xs[cb], bs[0], acc, p0, half, lane);
            else           compute_role<1, R>(xs[cb], bs[0], acc, p0, half, lane);
            __builtin_amdgcn_s_setprio(0);
        }
    }

    // ----- quant epilogue (exact fp32 op sequence; proven absmax 0.0) --------
    const int dv = dvds[layer];
    float add1 = ldexpf(1.0f, dv - 10);
    float inv1 = ldexpf(1.0f, -(dv - 9));
    const float relu = relus[layer];
    const int sk = (layer == 1) ? 4 : 3;
    const float bitsv = ldexpf(1.0f, bitsp[0]) - 1.0f;
    float clp, scl;
    {
        #pragma clang fp contract(off)
        clp = rintf(bitsv / relu * 33554432.0f);
        scl = floorf((relu + ldexpf(1.0f, sk - 1)) * ldexpf(1.0f, -sk));
    }
    float add2 = ldexpf(1.0f, 24 - sk);
    float inv2 = ldexpf(1.0f, -(25 - sk));

    const int co = n0 + (lane & 31);
    float bq = rintf(bias[co]);
    float mm = muls[co];
    // wave's two parities: role0 -> {EE=0, OO=3}; role1 -> {EO=1, OE=2}
    int pmap[2];
    pmap[0] = role == 0 ? 0 : 1;
    pmap[1] = role == 0 ? 3 : 2;
    // tapsum = sum of QS per-qs partials (exact integer adds; no atomics)
    int fullp[2] = {0, 0};
    for (int q = 0; q < QS; ++q) {
        fullp[0] += tsp[(q * 4 + pmap[0]) * Cout + co];
        fullp[1] += tsp[(q * 4 + pmap[1]) * Cout + co];
    }

    const int Wout = Wq * 2;

    #pragma unroll
    for (int r = 0; r < R; ++r) {
        #pragma unroll
        for (int a = 0; a < 2; ++a) {
            const int p = pmap[a];
            const int py = p >> 1, px = p & 1;
            #pragma unroll
            for (int reg = 0; reg < 16; ++reg) {
                const int mrow = (reg & 3) + 8 * (reg >> 2) + 4 * (lane >> 5);
                const int qy2 = qy0 + (pairId * R + r) * 2 + (mrow >> 4);
                const int qx2 = qx0 + (mrow & 15);
                float v = (float)(acc[r][a][reg] + 128 * fullp[a]);
                int iv;
                {
                    #pragma clang fp contract(off)
                    v = (v + bq) * mm;
                    v = floorf((v + add1) * inv1);
                    v = fminf(fmaxf(v, 0.0f), clp);
                    iv = (int)((v * scl + add2) * inv2);   // trunc == floor (v>=0)
                }
                const int oy = 2 * qy2 + py, ox = 2 * qx2 + px;
                outp[((size_t)oy * Wout + ox) * Cout + co] = (signed char)(iv - 128);
            }
        }
    }
}

// Final layer: N = (parity,co) columns, 1 MFMA per shift, R=2, MW=4 (576
// blocks); x+b DMA double-buffered, 1 barrier/chunk; output staged in LDS
// (obuf aliases dead xs/bs after K-loop) then stored as 128B-contiguous rows.
__global__ __launch_bounds__(256, 4)
void deconv_final_v23(const signed char* __restrict__ xin, const signed char* __restrict__ wpk,
                      const float* __restrict__ bias, const float* __restrict__ muls,
                      const int* __restrict__ tsum, const int* __restrict__ dvds,
                      const signed char* __restrict__ xpad,
                      int Cin, int Hq, int Wq, float* __restrict__ outp) {
    constexpr int R = 2, MW = 4;
    constexpr int QROWS = MW * R * 2;      // 16
    constexpr int NROW = QROWS + 2;        // 18
    constexpr int NPIX = NROW * 18;        // 324
    constexpr int THREADS = 256;
    constexpr int XC = NPIX * 2;           // 648
    constexpr int XI = (XC + THREADS - 1) / THREADS;   // 3
    constexpr int BC = 576;
    constexpr int BI = (BC + THREADS - 1) / THREADS;   // 3
    constexpr int XBUF = NPIX * 32;        // 10368

    // xs/bs during K-loop; obuf (3x32x32 f32 = 12,288B) aliases them after.
    __shared__ __align__(16) signed char smem[2 * XBUF + 2 * 9216]; // 39,168
    signed char (*xs)[XBUF] = (signed char(*)[XBUF])smem;
    signed char (*bs)[9216] = (signed char(*)[9216])(smem + 2 * XBUF);
    float* obuf = (float*)smem;

    const int tid  = threadIdx.x;
    const int lane = tid & 63;
    const int wid  = tid >> 6;
    const int qx0  = blockIdx.y * 16;
    const int qy0  = blockIdx.z * QROWS;

    int16v acc[R];
    #pragma unroll
    for (int r = 0; r < R; ++r)
        #pragma unroll
        for (int e = 0; e < 16; ++e) acc[r][e] = 0;

    const int half   = lane >> 5;
    const int rowbit = (lane >> 4) & 1;
    const int col    = lane & 15;
    int p0[R];
    #pragma unroll
    for (int r = 0; r < R; ++r)
        p0[r] = ((wid * R + r) * 2 + rowbit) * 18 + col;

    const signed char* xsrc[XI];
    #pragma unroll
    for (int t = 0; t < XI; ++t) {
        int i = tid + t * THREADS;
        xsrc[t] = xpad;
        if (i < XC) {
            int pix = i >> 1, g = i & 1;
            int rr = pix / 18, cc = pix - rr * 18;
            int y = qy0 - 1 + rr, xx = qx0 - 1 + cc;
            bool ok = (unsigned)y < (unsigned)Hq && (unsigned)xx < (unsigned)Wq;
            xsrc[t] = ok ? (xin + ((size_t)y * Wq + xx) * Cin + g * 16)
                         : (xpad + g * 16);
        }
    }

    auto dma_x = [&](int ck, int b) {
        #pragma unroll
        for (int t = 0; t < XI; ++t) {
            int i = tid + t * THREADS;
            if (i < XC) dma16(xsrc[t] + ck, &xs[b][i * 16]);
        }
    };
    auto dma_b = [&](int cs, int b) {
        const signed char* ws = wpk + (size_t)cs * 9216;
        #pragma unroll
        for (int t = 0; t < BI; ++t) {
            int i = tid + t * THREADS;
            if (i < BC) dma16(ws + (size_t)i * 16, &bs[b][i * 16]);
        }
    };

    dma_x(0, 0);
    dma_b(0, 0);
    for (int ck = 0; ck < Cin; ck += 32) {
        const int cb = (ck >> 5) & 1;
        __syncthreads();
        if (ck + 32 < Cin) {
            dma_x(ck + 32, cb ^ 1);
            dma_b((ck >> 5) + 1, cb ^ 1);
        }
        __builtin_amdgcn_s_setprio(1);
        #pragma unroll
        for (int s9 = 0; s9 < 9; ++s9) {
            const int dy = s9 / 3, dx = s9 % 3;
            int4v b = *(const int4v*)&bs[cb][s9 * 1024 + lane * 16];
            #pragma unroll
            for (int r = 0; r < R; ++r) {
                int4v a = *(const int4v*)&xs[cb][(p0[r] + dy * 18 + dx) * 32 + half * 16];
                acc[r] = __builtin_amdgcn_mfma_i32_32x32x32_i8(a, b, acc[r], 0, 0, 0);
            }
        }
        __builtin_amdgcn_s_setprio(0);
    }

    const int dv = dvds[3];
    const float add1 = ldexpf(1.0f, dv - 9);
    const float inv1 = ldexpf(1.0f, -(dv - 8));

    const int coln = lane & 31;
    const int co = coln & 7;
    const int p  = coln >> 3;
    const int py = p >> 1, px = p & 1;
    const bool valid = (co < 3);
    float bq = 0.f, mm = 0.f;
    int fp = 0;
    if (valid) { bq = rintf(bias[co]); mm = muls[co]; fp = tsum[p * 3 + co]; }

    __syncthreads();   // all waves done reading xs/bs (obuf aliases them)

    // epilogue -> obuf[co][ly][lx] (local 32x32 px block per co plane)
    #pragma unroll
    for (int r = 0; r < R; ++r) {
        #pragma unroll
        for (int reg = 0; reg < 16; ++reg) {
            const int mrow = (reg & 3) + 8 * (reg >> 2) + 4 * (lane >> 5);
            const int lq_y = (wid * R + r) * 2 + (mrow >> 4);   // 0..15
            const int lq_x = mrow & 15;                          // 0..15
            float v = (float)(acc[r][reg] + 128 * fp);
            {
                #pragma clang fp contract(off)
                v = (v + bq) * mm;
                v = floorf((v + add1) * inv1);   // keep floorf: v may be negative
                v = v / 255.0f;
            }
            if (valid) {
                const int ly = 2 * lq_y + py, lx = 2 * lq_x + px;
                obuf[co * 1024 + ly * 32 + lx] = v;
            }
        }
    }
    __syncthreads();

    // coalesced store: 3072 floats = 96 rows of 32 floats (128B contiguous)
    const int Wout = Wq * 2, Hout = Hq * 2;
    const int oyb = qy0 * 2, oxb = qx0 * 2;
    #pragma unroll
    for (int k = 0; k < 12; ++k) {
        const int idx = tid + k * 256;
        const int c  = idx >> 10;
        const int rem = idx & 1023;
        const int ly = rem >> 5, lx = rem & 31;
        outp[((size_t)c * Hout + oyb + ly) * Wout + oxb + lx] = obuf[idx];
    }
}

extern "C" void kernel_launch(void* const* d_in, const int* in_sizes, int n_in,
                              void* d_out, int out_size, void* d_ws, size_t ws_size,
                              hipStream_t stream) {
    const float* x  = (const float*)d_in[0];
    const float* w1 = (const float*)d_in[1];
    const float* b1 = (const float*)d_in[2];
    const float* w2 = (const float*)d_in[3];
    const float* b2 = (const float*)d_in[4];
    const float* w3 = (const float*)d_in[5];
    const float* b3 = (const float*)d_in[6];
    const float* w4 = (const float*)d_in[7];
    const float* b4 = (const float*)d_in[8];
    const float* m0 = (const float*)d_in[9];
    const float* m1 = (const float*)d_in[10];
    const float* m2 = (const float*)d_in[11];
    const float* m3 = (const float*)d_in[12];
    const float* relus = (const float*)d_in[13];
    const int* dvds = (const int*)d_in[14];
    const int* bitsp = (const int*)d_in[15];

    signed char* wsb = (signed char*)d_ws;
    size_t o = 0;
    signed char* wpk1 = wsb + o; o += (size_t)10 * 6 * 25600;   // 1,536,000
    signed char* wpk2 = wsb + o; o += (size_t)6 * 6 * 25600;    //   921,600
    signed char* wpk3 = wsb + o; o += (size_t)6 * 6 * 25600;
    signed char* wpk4 = wsb + o; o += (size_t)6 * 9216;         //    55,296
    // per-qs tapsum partials (plain stores, no zeroing needed)
    int* tsp1 = (int*)(wsb + o); o += 10 * 4 * 192 * 4;         // 30,720
    int* tsp2 = (int*)(wsb + o); o += 6 * 4 * 192 * 4;          // 18,432
    int* tsp3 = (int*)(wsb + o); o += 6 * 4 * 192 * 4;
    int* ts4  = (int*)(wsb + o); o += 4 * 4 * 4;                //      64
    o = (o + 15) & ~(size_t)15;
    signed char* xpad = wsb + o; o += 512;                      // -128 halo pad
    signed char* xh = wsb + o; o += (size_t)48 * 48 * 320;
    signed char* a1 = wsb + o; o += (size_t)96 * 96 * 192;
    signed char* a2 = wsb + o; o += (size_t)192 * 192 * 192;
    signed char* a3 = wsb + o; o += (size_t)384 * 384 * 192;

    // convert || packA || pack_w4 || tap_w4 || xpad-fill (independent)
    prep_all<<<372, 256, 0, stream>>>(x, xh, w1, w2, w3, w4,
                                      wpk1, wpk2, wpk3, wpk4,
                                      tsp1, tsp2, tsp3, ts4, (int*)xpad);

    // layer 1: 48x48x320 -> 96x96x192 (R=1: 4-row tiles, 216 blocks, dbuf-b)
    deconv_v23<4, 1, true, 0><<<216, 256, 0, stream>>>(
        xh, wpk1, b1, m0, tsp1, 10, relus, dvds, bitsp, xpad, 0, 320, 192, 6, 48, 48,
        /*NB*/6, /*NQX*/3, /*T8*/0, a1);
    // layer 2: 96x96x192 -> 192x192x192 (R=2: 8-row tiles, 432 blocks, single-b)
    deconv_v23<4, 2, false, 1><<<432, 256, 0, stream>>>(
        a1, wpk2, b2, m1, tsp2, 6, relus, dvds, bitsp, xpad, 1, 192, 192, 6, 96, 96,
        6, 6, 0, a2);
    // layer 3: 192x192x192 -> 384x384x192 (R=2: 8-row tiles, 1728 blocks =
    // 8 XCDs x 36 tiles x 6 nb, single-b; ~1.9MB/XCD L2-resident)
    deconv_v23<4, 2, false, 2><<<1728, 256, 0, stream>>>(
        a2, wpk3, b3, m2, tsp3, 6, relus, dvds, bitsp, xpad, 2, 192, 192, 6, 192, 192,
        6, 12, 36, a3);
    // layer 4: 384x384x192 -> 3x768x768 (R=2: 576 blocks; f32 NCHW via
    // LDS-staged coalesced stores)
    deconv_final_v23<<<dim3(1, 24, 24), 256, 0, stream>>>(
        a3, wpk4, b4, m3, ts4, dvds, xpad, 192, 384, 384, (float*)d_out);
}